// Round 1
// baseline (773.610 us; speedup 1.0000x reference)
//
#include <hip/hip_runtime.h>
#include <math.h>

// Problem constants (from reference)
#define B_     1024
#define H_     200
#define W_     32
#define COUT_  16
#define TOPK_  50

#define LDS_STRIDE 33   // 32 + 1 pad: column reads (fixed w, h varies by lane)
                        // land on distinct banks; stride 32 would be a
                        // 64-way bank conflict (all lanes -> bank w).

__global__ __launch_bounds__(256) void cnn_topk_kernel(
    const float* __restrict__ x,     // [B,1,H,W]
    const float* __restrict__ cw,    // [COUT,1,3,1]
    const float* __restrict__ cb,    // [COUT]
    float* __restrict__ out)         // [B,COUT,TOPK,W]
{
    // x tile with one zero halo row above and below (same-pad conv, PAD=1)
    __shared__ float xs[(H_ + 2) * LDS_STRIDE];

    const int b   = blockIdx.x;
    const int tid = threadIdx.x;
    const float* xb = x + (size_t)b * (H_ * W_);

    // Stage x[b] -> LDS (global reads coalesced; LDS writes conflict-free:
    // addr % 32 = (h + w + 1) % 32 covers all banks within each wave)
    for (int i = tid; i < H_ * W_; i += 256) {
        int h = i >> 5, w = i & 31;
        xs[(h + 1) * LDS_STRIDE + w] = xb[i];
    }
    if (tid < W_) {
        xs[tid] = 0.0f;                                // row h = -1
        xs[(H_ + 1) * LDS_STRIDE + tid] = 0.0f;        // row h = H
    }
    __syncthreads();

    const int wave = tid >> 6;
    const int lane = tid & 63;

    // Each wave owns columns w = wave, wave+4, ... (8 columns), all 16 co each.
    for (int w = wave; w < W_; w += 4) {
        // Hoist the x column taps for this w (shared across all 16 co).
        float xm[4], xc[4], xp[4];
#pragma unroll
        for (int r = 0; r < 4; ++r) {
            int h = r * 64 + lane;           // logical conv-output row
            if (h < H_) {
                // LDS row (h) holds x[h-1] because of the +1 halo offset
                xm[r] = xs[ h      * LDS_STRIDE + w];
                xc[r] = xs[(h + 1) * LDS_STRIDE + w];
                xp[r] = xs[(h + 2) * LDS_STRIDE + w];
            } else {
                xm[r] = xc[r] = xp[r] = 0.0f;
            }
        }

        for (int co = 0; co < COUT_; ++co) {
            const float w0   = cw[co * 3 + 0];
            const float w1   = cw[co * 3 + 1];
            const float w2   = cw[co * 3 + 2];
            const float bias = cb[co];

            float v[4];
#pragma unroll
            for (int r = 0; r < 4; ++r) {
                int h = r * 64 + lane;
                float s = bias + w0 * xm[r] + w1 * xc[r] + w2 * xp[r];
                // tanh(s) = 1 - 2/(exp(2s)+1); exact enough (~1e-6) vs 1.9e-2 tol
                float e = __expf(2.0f * s);
                float t = 1.0f - 2.0f / (e + 1.0f);
                v[r] = (h < H_) ? t : -2.0f;   // pad below any tanh value
            }

            // Bitonic sort, descending, over 256 elements: i = r*64 + lane.
            // j < 64  : partner in another lane, same reg  -> __shfl_xor
            // j >= 64 : partner in another reg, same lane  -> register swap
#pragma unroll
            for (int k = 2; k <= 256; k <<= 1) {
#pragma unroll
                for (int j = k >> 1; j > 0; j >>= 1) {
                    if (j < 64) {
#pragma unroll
                        for (int r = 0; r < 4; ++r) {
                            float o = __shfl_xor(v[r], j, 64);
                            int i = r * 64 + lane;
                            bool take_max = (((i & j) == 0) == ((i & k) == 0));
                            v[r] = take_max ? fmaxf(v[r], o) : fminf(v[r], o);
                        }
                    } else {
                        int rj = j >> 6;   // 1 or 2
#pragma unroll
                        for (int r = 0; r < 4; ++r) {
                            int pr = r ^ rj;
                            if (pr > r) {  // r is the "lo" element (bit j clear)
                                int i = r * 64 + lane;
                                bool desc = ((i & k) == 0);
                                float a = v[r], bb = v[pr];
                                v[r]  = desc ? fmaxf(a, bb) : fminf(a, bb);
                                v[pr] = desc ? fminf(a, bb) : fmaxf(a, bb);
                            }
                        }
                    }
                }
            }

            // Descending order: sorted position == element index; top-50 in r=0.
            if (lane < TOPK_) {
                out[(((size_t)b * COUT_ + co) * TOPK_ + lane) * W_ + w] = v[0];
            }
        }
    }
}

extern "C" void kernel_launch(void* const* d_in, const int* in_sizes, int n_in,
                              void* d_out, int out_size, void* d_ws, size_t ws_size,
                              hipStream_t stream) {
    const float* x  = (const float*)d_in[0];   // [1024,1,200,32]
    const float* cw = (const float*)d_in[1];   // [16,1,3,1]
    const float* cb = (const float*)d_in[2];   // [16]
    float* out = (float*)d_out;                // [1024,16,50,32]

    cnn_topk_kernel<<<dim3(B_), dim3(256), 0, stream>>>(x, cw, cb, out);
}

// Round 2
// 435.055 us; speedup vs baseline: 1.7782x; 1.7782x over previous
//
#include <hip/hip_runtime.h>
#include <math.h>

// Problem constants (from reference)
#define B_     1024
#define H_     200
#define W_     32
#define COUT_  16
#define TOPK_  50

#define LDS_STRIDE 33   // 32 + 1 pad: column reads (fixed w, h varies by lane)
                        // hit distinct banks; stride 32 would be 64-way conflict.

// Cross-lane XOR exchange. DPP (VALU pipe, free of LDS pipe) for j=1,2,8;
// ds_swizzle (LDS pipe, but no address VGPR) for j=4,16; ds_bpermute for j=32.
//   xor1 = quad_perm [1,0,3,2] = 0xB1
//   xor2 = quad_perm [2,3,0,1] = 0x4E
//   xor8 = row_ror:8 (rotate by 8 within 16-row == xor 8) = 0x128
template<int J>
__device__ __forceinline__ float lane_xor(float v) {
    int x = __float_as_int(v);
    int r;
    if constexpr (J == 1)       r = __builtin_amdgcn_update_dpp(x, x, 0xB1, 0xF, 0xF, true);
    else if constexpr (J == 2)  r = __builtin_amdgcn_update_dpp(x, x, 0x4E, 0xF, 0xF, true);
    else if constexpr (J == 8)  r = __builtin_amdgcn_update_dpp(x, x, 0x128, 0xF, 0xF, true);
    else if constexpr (J == 4)  r = __builtin_amdgcn_ds_swizzle(x, 0x101F); // xor4, and=0x1f
    else if constexpr (J == 16) r = __builtin_amdgcn_ds_swizzle(x, 0x401F); // xor16
    else {                      // J == 32: crosses 32-lane swizzle groups
        int lane = (int)(threadIdx.x & 63);
        r = __builtin_amdgcn_ds_bpermute((lane ^ 32) << 2, x);
    }
    return __int_as_float(r);
}

// Compare-exchange: keep max at this lane iff take_max.
// codegen: v_cmp + s_xnor(mask, hoisted lane-mask) + v_cndmask = 2 VALU + 1 SALU.
template<int J>
__device__ __forceinline__ void ce(float& v, bool take_max) {
    float o = lane_xor<J>(v);
    v = ((v < o) == take_max) ? o : v;
}

// One bitonic-sort stage (level j of block k) applied to chunks 0..2.
// Chunk r sort direction: r even -> ascending, r odd -> descending.
// take_max = ((lane&j)!=0) == up,  up = ((lane&k)==0) == asc.
#define CE4_3(J, K)                                                       \
  { const bool bj = (lane & (J)) != 0; const bool bk = (lane & (K)) == 0; \
    ce<J>(v[0], bj == bk);                                                \
    ce<J>(v[1], bj == (!bk));                                             \
    ce<J>(v[2], bj == bk); }

// Chunk 3 has only 8 real values (h=192..199) in lanes 0..7; sort-8 desc.
#define CE3(J, K)                                                         \
  { const bool bj = (lane & (J)) != 0; const bool bk = (lane & (K)) == 0; \
    ce<J>(v[3], bj == (!bk)); }

__global__ __launch_bounds__(256) void cnn_topk_kernel(
    const float* __restrict__ x,     // [B,1,H,W]
    const float* __restrict__ cw,    // [COUT,1,3,1]
    const float* __restrict__ cb,    // [COUT]
    float* __restrict__ out)         // [B,COUT,TOPK,W]
{
    __shared__ float xs[(H_ + 2) * LDS_STRIDE];

    const int b  = blockIdx.x >> 1;    // batch
    const int wh = blockIdx.x & 1;     // which 16-column half
    const int tid = threadIdx.x;
    const float* xb = x + (size_t)b * (H_ * W_);

    // Stage x[b] -> LDS with zero halo rows (same-pad conv, PAD=1)
    for (int i = tid; i < H_ * W_; i += 256) {
        int h = i >> 5, w = i & 31;
        xs[(h + 1) * LDS_STRIDE + w] = xb[i];
    }
    if (tid < W_) {
        xs[tid] = 0.0f;
        xs[(H_ + 1) * LDS_STRIDE + tid] = 0.0f;
    }
    __syncthreads();

    const int wave = tid >> 6;
    const int lane = tid & 63;

    for (int wi = 0; wi < 4; ++wi) {
        const int w = wh * 16 + wave * 4 + wi;

        // Hoist x-column taps (shared by all 16 co). LDS row h holds x[h-1].
        float xm[4], xc[4], xp[4];
#pragma unroll
        for (int r = 0; r < 4; ++r) {
            int h = r * 64 + lane;
            if (h < H_) {
                xm[r] = xs[ h      * LDS_STRIDE + w];
                xc[r] = xs[(h + 1) * LDS_STRIDE + w];
                xp[r] = xs[(h + 2) * LDS_STRIDE + w];
            } else {
                xm[r] = xc[r] = xp[r] = 0.0f;
            }
        }

        for (int co = 0; co < COUT_; ++co) {
            const float w0   = cw[co * 3 + 0];
            const float w1   = cw[co * 3 + 1];
            const float w2   = cw[co * 3 + 2];
            const float bias = cb[co];

            float v[4];
#pragma unroll
            for (int r = 0; r < 4; ++r) {
                float s = fmaf(w2, xp[r], fmaf(w1, xc[r], fmaf(w0, xm[r], bias)));
                // tanh(s) = 1 - 2/(exp(2s)+1)
                float e = __expf(2.0f * s);
                float t = fmaf(-2.0f, __builtin_amdgcn_rcpf(e + 1.0f), 1.0f);
                v[r] = (r * 64 + lane < H_) ? t : -2.0f;  // pad below tanh range
            }

            // --- sort chunks 0..2 (64 elements each): asc, desc, asc ---
            CE4_3(1, 2)
            CE4_3(2, 4)  CE4_3(1, 4)
            CE4_3(4, 8)  CE4_3(2, 8)  CE4_3(1, 8)
            CE4_3(8, 16) CE4_3(4, 16) CE4_3(2, 16) CE4_3(1, 16)
            CE4_3(16,32) CE4_3(8, 32) CE4_3(4, 32) CE4_3(2, 32) CE4_3(1, 32)
            CE4_3(32,64) CE4_3(16,64) CE4_3(8, 64) CE4_3(4, 64) CE4_3(2, 64) CE4_3(1, 64)

            // --- chunk 3: sort-8 desc over lanes 0..7 (rest are -2 sentinels) ---
            CE3(1, 2)
            CE3(2, 4)  CE3(1, 4)
            CE3(4, 8)  CE3(2, 8)  CE3(1, 8)

            // --- top-64 merges (bitonic halving) ---
            // [v0 asc, v1 desc] bitonic -> pairwise max = top-64, bitonic
            float m1 = fmaxf(v[0], v[1]);
            float m2 = fmaxf(v[2], v[3]);
            // sort m1 asc, m2 desc (bitonic merge, uniform direction)
#define MM(J) { const bool bj = (lane & (J)) != 0; ce<J>(m1, bj); ce<J>(m2, !bj); }
            MM(32) MM(16) MM(8) MM(4) MM(2) MM(1)
#undef MM
            // [m1 asc, m2 desc] bitonic -> pairwise max = top-64 of 256
            float t = fmaxf(m1, m2);
#define MT(J) { const bool bj = (lane & (J)) != 0; ce<J>(t, !bj); }
            MT(32) MT(16) MT(8) MT(4) MT(2) MT(1)
#undef MT

            if (lane < TOPK_) {
                out[(((size_t)b * COUT_ + co) * TOPK_ + lane) * W_ + w] = t;
            }
        }
    }
}

extern "C" void kernel_launch(void* const* d_in, const int* in_sizes, int n_in,
                              void* d_out, int out_size, void* d_ws, size_t ws_size,
                              hipStream_t stream) {
    const float* x  = (const float*)d_in[0];   // [1024,1,200,32]
    const float* cw = (const float*)d_in[1];   // [16,1,3,1]
    const float* cb = (const float*)d_in[2];   // [16]
    float* out = (float*)d_out;                // [1024,16,50,32]

    cnn_topk_kernel<<<dim3(B_ * 2), dim3(256), 0, stream>>>(x, cw, cb, out);
}

// Round 4
// 350.401 us; speedup vs baseline: 2.2078x; 1.2416x over previous
//
#include <hip/hip_runtime.h>
#include <math.h>

// Problem constants (from reference)
#define B_     1024
#define H_     200
#define W_     32
#define COUT_  16
#define TOPK_  50

#define LDS_STRIDE 33   // 32 + 1 pad for the x tile: column reads conflict-free
#define OB_STRIDE  17   // 16 + 1 pad for the packed output buffer

// Native packed-half vector type (avoids ROCm __half2 overload gaps).
typedef _Float16 h2 __attribute__((ext_vector_type(2)));
union HU { h2 h; int i; };

// Cross-lane XOR exchange on a 32-bit value.
// DPP (VALU pipe) for j=1,2,8; ds_swizzle for j=4,16; ds_bpermute for j=32.
template<int J>
__device__ __forceinline__ int lane_xor_i(int x) {
    if constexpr (J == 1)  return __builtin_amdgcn_update_dpp(x, x, 0xB1, 0xF, 0xF, true);  // quad_perm [1,0,3,2]
    else if constexpr (J == 2)  return __builtin_amdgcn_update_dpp(x, x, 0x4E, 0xF, 0xF, true);  // quad_perm [2,3,0,1]
    else if constexpr (J == 8)  return __builtin_amdgcn_update_dpp(x, x, 0x128, 0xF, 0xF, true); // row_ror:8 == xor8
    else if constexpr (J == 4)  return __builtin_amdgcn_ds_swizzle(x, 0x101F); // BitMode xor=4
    else if constexpr (J == 16) return __builtin_amdgcn_ds_swizzle(x, 0x401F); // BitMode xor=16
    else { // J == 32 crosses the 32-lane swizzle groups
        int lane = (int)(threadIdx.x & 63);
        return __builtin_amdgcn_ds_bpermute((lane ^ 32) << 2, x);
    }
}

// Packed compare-exchange: two independent sequences in the f16 halves.
// exchange + v_pk_max_f16 + v_pk_min_f16 + v_cndmask_b32 = 4 ops / 2 seqs.
template<int J>
__device__ __forceinline__ void ce2(h2& v, bool take_max) {
    HU a; a.h = v;
    HU o; o.i = lane_xor_i<J>(a.i);
    h2 mx = __builtin_elementwise_max(v, o.h);   // v_pk_max_f16
    h2 mn = __builtin_elementwise_min(v, o.h);   // v_pk_min_f16
    v = take_max ? mx : mn;                      // v_cndmask_b32
}

// Bitonic stage (level J of block K) on chunks 0..2 (asc, desc, asc).
#define CE4_3(J, K)                                                        \
  { const bool bj = (lane & (J)) != 0; const bool bk = (lane & (K)) == 0;  \
    ce2<J>(v[0], bj == bk);                                                \
    ce2<J>(v[1], bj != bk);                                                \
    ce2<J>(v[2], bj == bk); }

// Chunk 3: only 8 real values (h=192..199), sort-8 descending.
#define CE3(J, K)                                                          \
  { const bool bj = (lane & (J)) != 0; const bool bk = (lane & (K)) == 0;  \
    ce2<J>(v[3], bj != bk); }

__device__ __forceinline__ float fast_tanh(float s) {
    // tanh(s) = 1 - 2/(exp(2s)+1)
    float e = __expf(2.0f * s);
    return fmaf(-2.0f, __builtin_amdgcn_rcpf(e + 1.0f), 1.0f);
}

__global__ __launch_bounds__(256) void cnn_topk_kernel(
    const float* __restrict__ x,     // [B,1,H,W]
    const float* __restrict__ cw,    // [COUT,1,3,1]
    const float* __restrict__ cb,    // [COUT]
    float* __restrict__ out)         // [B,COUT,TOPK,W]
{
    // Union: phase A = x tile (6666 floats), phase B = packed out buffer
    // (8 co-pairs x 50 k x 17 stride = 6800 ints). Max 27200 B.
    __shared__ int smem[8 * TOPK_ * OB_STRIDE];
    float* xs  = (float*)smem;
    int* obuf  = smem;

    const int b   = blockIdx.x >> 1;   // batch
    const int wh  = blockIdx.x & 1;    // 16-column half
    const int tid = threadIdx.x;
    const float* xb = x + (size_t)b * (H_ * W_);

    // ---- Phase A: stage x[b] -> LDS with zero halo rows (same-pad, PAD=1) ----
    for (int i = tid; i < H_ * W_; i += 256) {
        int h = i >> 5, w = i & 31;
        xs[(h + 1) * LDS_STRIDE + w] = xb[i];
    }
    if (tid < W_) {
        xs[tid] = 0.0f;
        xs[(H_ + 1) * LDS_STRIDE + tid] = 0.0f;
    }
    __syncthreads();

    const int wave = tid >> 6;
    const int lane = tid & 63;

    // Hoist conv taps for ALL 4 owned columns into registers (xs dies after).
    float xm[4][4], xc[4][4], xp[4][4];
#pragma unroll
    for (int wi = 0; wi < 4; ++wi) {
        const int w = wh * 16 + wave * 4 + wi;
#pragma unroll
        for (int r = 0; r < 4; ++r) {
            int h = r * 64 + lane;
            if (h < H_) {   // LDS row h holds x[h-1] (halo offset)
                xm[wi][r] = xs[ h      * LDS_STRIDE + w];
                xc[wi][r] = xs[(h + 1) * LDS_STRIDE + w];
                xp[wi][r] = xs[(h + 2) * LDS_STRIDE + w];
            } else {
                xm[wi][r] = xc[wi][r] = xp[wi][r] = 0.0f;
            }
        }
    }
    __syncthreads();   // xs reads done everywhere; smem becomes obuf

    // ---- Phase B: conv + tanh + packed bitonic top-50 per co-pair ----
    for (int cp = 0; cp < 8; ++cp) {
        const int coA = 2 * cp, coB = 2 * cp + 1;
        const float w0A = cw[coA * 3], w1A = cw[coA * 3 + 1], w2A = cw[coA * 3 + 2], bA = cb[coA];
        const float w0B = cw[coB * 3], w1B = cw[coB * 3 + 1], w2B = cw[coB * 3 + 2], bB = cb[coB];

#pragma unroll
        for (int wi = 0; wi < 4; ++wi) {
            h2 v[4];
#pragma unroll
            for (int r = 0; r < 4; ++r) {
                float sA = fmaf(w2A, xp[wi][r], fmaf(w1A, xc[wi][r], fmaf(w0A, xm[wi][r], bA)));
                float sB = fmaf(w2B, xp[wi][r], fmaf(w1B, xc[wi][r], fmaf(w0B, xm[wi][r], bB)));
                h2 p;
                p.x = (_Float16)fast_tanh(sA);
                p.y = (_Float16)fast_tanh(sB);
                h2 s2; s2.x = (_Float16)(-2.0f); s2.y = (_Float16)(-2.0f);
                v[r] = (r * 64 + lane < H_) ? p : s2;   // sentinel below tanh range
            }

            // sort chunks 0..2 (asc, desc, asc), 21 stages
            CE4_3(1, 2)
            CE4_3(2, 4)  CE4_3(1, 4)
            CE4_3(4, 8)  CE4_3(2, 8)  CE4_3(1, 8)
            CE4_3(8, 16) CE4_3(4, 16) CE4_3(2, 16) CE4_3(1, 16)
            CE4_3(16,32) CE4_3(8, 32) CE4_3(4, 32) CE4_3(2, 32) CE4_3(1, 32)
            CE4_3(32,64) CE4_3(16,64) CE4_3(8, 64) CE4_3(4, 64) CE4_3(2, 64) CE4_3(1, 64)

            // chunk 3: sort-8 descending (lanes 0..7 real, rest sentinel)
            CE3(1, 2)
            CE3(2, 4)  CE3(1, 4)
            CE3(4, 8)  CE3(2, 8)  CE3(1, 8)

            // top-64 merges
            h2 m1 = __builtin_elementwise_max(v[0], v[1]);   // bitonic
            h2 m2 = __builtin_elementwise_max(v[2], v[3]);   // bitonic
#define MM(J) { const bool bj = (lane & (J)) != 0; ce2<J>(m1, bj); ce2<J>(m2, !bj); }
            MM(32) MM(16) MM(8) MM(4) MM(2) MM(1)
#undef MM
            h2 t = __builtin_elementwise_max(m1, m2);        // top-64 of 256, bitonic
#define MT(J) { const bool bj = (lane & (J)) != 0; ce2<J>(t, !bj); }
            MT(32) MT(16) MT(8) MT(4) MT(2) MT(1)
#undef MT

            if (lane < TOPK_) {
                HU u; u.h = t;
                obuf[(cp * TOPK_ + lane) * OB_STRIDE + (wave * 4 + wi)] = u.i;
            }
        }
    }
    __syncthreads();

    // ---- Phase C: coalesced write-out. 6400 packed entries = 25 iters/thread.
    // Entry (cp,k,w) -> out rows co=2cp (lo half) and co=2cp+1 (hi half).
    const size_t obase = (size_t)b * (COUT_ * TOPK_ * W_) + wh * 16;
    for (int j = 0; j < 25; ++j) {
        int idx = tid + j * 256;          // [cp][k][w], w in low 4 bits
        int cp  = idx / 800;
        int rem = idx - cp * 800;
        int k   = rem >> 4;
        int w   = rem & 15;
        HU u; u.i = obuf[(cp * TOPK_ + k) * OB_STRIDE + w];
        out[obase + ((size_t)(2 * cp)     * TOPK_ + k) * W_ + w] = (float)u.h.x;
        out[obase + ((size_t)(2 * cp + 1) * TOPK_ + k) * W_ + w] = (float)u.h.y;
    }
}

extern "C" void kernel_launch(void* const* d_in, const int* in_sizes, int n_in,
                              void* d_out, int out_size, void* d_ws, size_t ws_size,
                              hipStream_t stream) {
    const float* x  = (const float*)d_in[0];   // [1024,1,200,32]
    const float* cw = (const float*)d_in[1];   // [16,1,3,1]
    const float* cb = (const float*)d_in[2];   // [16]
    float* out = (float*)d_out;                // [1024,16,50,32]

    cnn_topk_kernel<<<dim3(B_ * 2), dim3(256), 0, stream>>>(x, cw, cb, out);
}

// Round 5
// 347.291 us; speedup vs baseline: 2.2276x; 1.0090x over previous
//
#include <hip/hip_runtime.h>
#include <math.h>

// Problem constants (from reference)
#define B_     1024
#define H_     200
#define W_     32
#define COUT_  16
#define TOPK_  50

#define XST 33   // x-tile stride (f32): column reads are 2-way bank aliased = free
#define OST 17   // obuf stride (16 + 1 pad)

typedef _Float16 h2 __attribute__((ext_vector_type(2)));
union HU { h2 h; int i; };

// Cross-lane XOR exchange on a 32-bit value.
// DPP (VALU pipe) for j=1,2,8; ds_swizzle for j=4,16; ds_bpermute for j=32.
template<int J>
__device__ __forceinline__ int lane_xor_i(int x) {
    if constexpr (J == 1)  return __builtin_amdgcn_update_dpp(x, x, 0xB1, 0xF, 0xF, true);  // quad_perm [1,0,3,2]
    else if constexpr (J == 2)  return __builtin_amdgcn_update_dpp(x, x, 0x4E, 0xF, 0xF, true);  // quad_perm [2,3,0,1]
    else if constexpr (J == 8)  return __builtin_amdgcn_update_dpp(x, x, 0x128, 0xF, 0xF, true); // row_ror:8 == xor8
    else if constexpr (J == 4)  return __builtin_amdgcn_ds_swizzle(x, 0x101F); // BitMode xor=4
    else if constexpr (J == 16) return __builtin_amdgcn_ds_swizzle(x, 0x401F); // BitMode xor=16
    else { // J == 32 crosses the 32-lane swizzle groups
        int lane = (int)(threadIdx.x & 63);
        return __builtin_amdgcn_ds_bpermute((lane ^ 32) << 2, x);
    }
}

__device__ __forceinline__ int pkmax(int a, int b) {
    HU x, y, r; x.i = a; y.i = b;
    r.h = __builtin_elementwise_max(x.h, y.h);   // v_pk_max_f16
    return r.i;
}
__device__ __forceinline__ int pkmin(int a, int b) {
    HU x, y, r; x.i = a; y.i = b;
    r.h = __builtin_elementwise_min(x.h, y.h);   // v_pk_min_f16
    return r.i;
}

// Packed compare-exchange on int-typed state: exchange + pk_max + pk_min +
// one 32-bit v_cndmask (mask is a hoisted SGPR pair). 4 ops / 2 sequences.
template<int J>
__device__ __forceinline__ void ce2(int& v, bool take_max) {
    int o  = lane_xor_i<J>(v);
    int mx = pkmax(v, o);
    int mn = pkmin(v, o);
    v = take_max ? mx : mn;
}

// Bitonic stage (level J of block K) on chunks 0..2 (asc, desc, asc).
// Uses hoisted bools j<J> = (lane&J)!=0, k<K> = (lane&K)==0.
#define CE4_3(J, K) { const bool tm = (j##J) == (k##K); \
    ce2<J>(v0, tm); ce2<J>(v1, !tm); ce2<J>(v2, tm); }

// Chunk 3: only 8 real values (h=192..199), sort-8 descending.
#define CE3(J, K) { ce2<J>(v3, (j##J) != (k##K)); }

__device__ __forceinline__ float fast_tanh(float s) {
    // tanh(s) = 1 - 2/(exp(2s)+1)
    float e = __expf(2.0f * s);
    return fmaf(-2.0f, __builtin_amdgcn_rcpf(e + 1.0f), 1.0f);
}

__global__ __launch_bounds__(256) void cnn_topk_kernel(
    const float* __restrict__ x,     // [B,1,H,W]
    const float* __restrict__ cw,    // [COUT,1,3,1]
    const float* __restrict__ cb,    // [COUT]
    float* __restrict__ out)         // [B,COUT,TOPK,W]
{
    __shared__ float xs[(H_ + 2) * XST];   // 26664 B, persistent (no aliasing)
    __shared__ int   obuf[TOPK_ * OST];    //  3400 B, per-cp packed results

    const int b   = blockIdx.x >> 1;   // batch
    const int wh  = blockIdx.x & 1;    // 16-column half
    const int tid = threadIdx.x;
    const float* xb = x + (size_t)b * (H_ * W_);

    // ---- stage x[b] -> LDS with zero halo rows (same-pad conv, PAD=1) ----
    for (int i = tid; i < H_ * W_; i += 256) {
        int h = i >> 5, w = i & 31;
        xs[(h + 1) * XST + w] = xb[i];
    }
    if (tid < W_) {
        xs[tid] = 0.0f;
        xs[(H_ + 1) * XST + tid] = 0.0f;
    }
    __syncthreads();

    const int wave = tid >> 6;
    const int lane = tid & 63;

    // Hoisted direction bools (each lives as one 64-bit SGPR-pair mask;
    // per-stage combos are i1 xors -> SALU, off the VALU pipe).
    const bool j1  = (lane & 1)  != 0;
    const bool j2  = (lane & 2)  != 0;
    const bool j4  = (lane & 4)  != 0;
    const bool j8  = (lane & 8)  != 0;
    const bool j16 = (lane & 16) != 0;
    const bool j32 = (lane & 32) != 0;
    const bool k2  = (lane & 2)  == 0;
    const bool k4  = (lane & 4)  == 0;
    const bool k8  = (lane & 8)  == 0;
    const bool k16 = (lane & 16) == 0;
    const bool k32 = (lane & 32) == 0;
    const bool k64 = true;             // (lane & 64) == 0 for lane < 64

    HU s2; s2.h.x = (_Float16)(-2.0f); s2.h.y = (_Float16)(-2.0f); // sentinel
    const int h3 = (192 + lane < H_) ? (192 + lane) : (H_ - 1);    // clamped tail row

    for (int cp = 0; cp < 8; ++cp) {
        const int coA = 2 * cp, coB = 2 * cp + 1;
        const float w0A = cw[coA * 3], w1A = cw[coA * 3 + 1], w2A = cw[coA * 3 + 2], bA = cb[coA];
        const float w0B = cw[coB * 3], w1B = cw[coB * 3 + 1], w2B = cw[coB * 3 + 2], bB = cb[coB];

#pragma unroll
        for (int wi = 0; wi < 4; ++wi) {
            const int w = wh * 16 + wave * 4 + wi;

            // conv + tanh, packed (co-pair in f16 halves). Taps re-read from
            // LDS per chunk: 12 ds_read_b32, 2-way bank aliasing = free.
            int v0, v1, v2, v3;
#define MAKE_V(VR, HROW)                                                     \
            {   const int hh = (HROW);                                       \
                float xm = xs[ hh      * XST + w];                           \
                float xc = xs[(hh + 1) * XST + w];                           \
                float xp = xs[(hh + 2) * XST + w];                           \
                float sA = fmaf(w2A, xp, fmaf(w1A, xc, fmaf(w0A, xm, bA)));  \
                float sB = fmaf(w2B, xp, fmaf(w1B, xc, fmaf(w0B, xm, bB)));  \
                HU u; u.h.x = (_Float16)fast_tanh(sA);                       \
                      u.h.y = (_Float16)fast_tanh(sB);                       \
                VR = u.i; }
            MAKE_V(v0, lane)
            MAKE_V(v1, 64 + lane)
            MAKE_V(v2, 128 + lane)
            MAKE_V(v3, h3)
#undef MAKE_V
            v3 = (lane < 8) ? v3 : s2.i;   // tail chunk: 8 real values

            // ---- sort chunks 0..2 (asc, desc, asc), 21 stages ----
            CE4_3(1, 2)
            CE4_3(2, 4)  CE4_3(1, 4)
            CE4_3(4, 8)  CE4_3(2, 8)  CE4_3(1, 8)
            CE4_3(8, 16) CE4_3(4, 16) CE4_3(2, 16) CE4_3(1, 16)
            CE4_3(16,32) CE4_3(8, 32) CE4_3(4, 32) CE4_3(2, 32) CE4_3(1, 32)
            CE4_3(32,64) CE4_3(16,64) CE4_3(8, 64) CE4_3(4, 64) CE4_3(2, 64) CE4_3(1, 64)

            // ---- chunk 3: sort-8 descending ----
            CE3(1, 2)
            CE3(2, 4)  CE3(1, 4)
            CE3(4, 8)  CE3(2, 8)  CE3(1, 8)

            // ---- top-64 merges ----
            int m1 = pkmax(v0, v1);     // bitonic
            int m2 = pkmax(v2, v3);     // bitonic
#define MM(J) { ce2<J>(m1, j##J); ce2<J>(m2, !(j##J)); }
            MM(32) MM(16) MM(8) MM(4) MM(2) MM(1)
#undef MM
            int t = pkmax(m1, m2);      // top-64 of 256, bitonic
#define MT(J) { ce2<J>(t, !(j##J)); }
            MT(32) MT(16) MT(8) MT(4) MT(2) MT(1)
#undef MT

            if (lane < TOPK_) obuf[lane * OST + (wave * 4 + wi)] = t;
        }
        __syncthreads();   // all 16 w of this cp in obuf

        // ---- coalesced write-out for this co-pair (800 entries) ----
#pragma unroll
        for (int j = 0; j < 4; ++j) {
            int idx = tid + j * 256;
            if (idx < 800) {
                int k = idx >> 4, w2 = idx & 15;
                HU u; u.i = obuf[k * OST + w2];
                size_t o0 = (((size_t)b * COUT_ + coA) * TOPK_ + k) * W_ + wh * 16 + w2;
                out[o0]                        = (float)u.h.x;
                out[o0 + (size_t)TOPK_ * W_]   = (float)u.h.y;
            }
        }
        __syncthreads();   // obuf free for next cp
    }
}

extern "C" void kernel_launch(void* const* d_in, const int* in_sizes, int n_in,
                              void* d_out, int out_size, void* d_ws, size_t ws_size,
                              hipStream_t stream) {
    const float* x  = (const float*)d_in[0];   // [1024,1,200,32]
    const float* cw = (const float*)d_in[1];   // [16,1,3,1]
    const float* cb = (const float*)d_in[2];   // [16]
    float* out = (float*)d_out;                // [1024,16,50,32]

    cnn_topk_kernel<<<dim3(B_ * 2), dim3(256), 0, stream>>>(x, cw, cb, out);
}